// Round 8
// baseline (832.963 us; speedup 1.0000x reference)
//
#include <hip/hip_runtime.h>

#define BB 64
#define LL 512
#define DD 1024
#define CC 131
#define CP 132
#define START_I 129
#define STOP_I 130
#define NEGV -10000.0f

// Raw workgroup barrier: makes LDS writes visible without draining vmcnt
// (so global stores/prefetches stay in flight across steps).
__device__ __forceinline__ void lds_barrier() {
    asm volatile("s_waitcnt lgkmcnt(0)" ::: "memory");
    __builtin_amdgcn_s_barrier();
    __builtin_amdgcn_sched_barrier(0);
}

// lane-broadcast read: value of lane `i` of this wave's register (const index)
#define RL(src, i) __int_as_float(__builtin_amdgcn_readlane(__float_as_int(src), (i)))

// ---------------- Kernel 1: feats[m][c] = dot(x[m,:], W[c,:]) + b[c] ----------------
// GM=64 -> 512 blocks = 2 blocks/CU: block A's staging overlaps block B's FMAs.
#define GM 64
#define GK 32
#define LSTR 36

__global__ __launch_bounds__(256, 2) void gemm_feats(
    const float* __restrict__ x, const float* __restrict__ W,
    const float* __restrict__ bias, float* __restrict__ feats)
{
    __shared__ float xs[GM * LSTR];   // [m][k] 64x36
    __shared__ float ws[CP * LSTR];   // [j][k] 132x36

    const int tid = threadIdx.x;
    const int m0 = blockIdx.x * GM;
    const int tm = tid & 15;          // rows tm + 16r (r<4)
    const int tj = (tid >> 4) & 15;   // cols tj + 16c (c<8)
    const bool tail = (tj < 3);
    const int tjt = (tj < 3) ? tj : 2;

    float acc[4][8];
    float acct[4];
#pragma unroll
    for (int r = 0; r < 4; ++r) {
        acct[r] = 0.f;
#pragma unroll
        for (int c = 0; c < 8; ++c) acc[r][c] = 0.f;
    }

    for (int kc = 0; kc < DD / GK; ++kc) {
        const int k0 = kc * GK;
        if (kc) __syncthreads();
#pragma unroll
        for (int q = 0; q < 2; ++q) {
            int lin = tid + q * 256;
            int m = lin >> 3, c4 = lin & 7;
            float4 v = *(const float4*)&x[(size_t)(m0 + m) * DD + k0 + c4 * 4];
            *(float4*)&xs[m * LSTR + c4 * 4] = v;
        }
#pragma unroll
        for (int q = 0; q < 5; ++q) {
            int lin = tid + q * 256;
            if (lin < CC * 8) {
                int r = lin >> 3, c4 = lin & 7;
                float4 v = *(const float4*)&W[(size_t)r * DD + k0 + c4 * 4];
                *(float4*)&ws[r * LSTR + c4 * 4] = v;
            }
        }
        __syncthreads();

#pragma unroll
        for (int k4 = 0; k4 < 8; ++k4) {
            float4 xr[4], wr[8], wt;
#pragma unroll
            for (int r = 0; r < 4; ++r)
                xr[r] = *(const float4*)&xs[(tm + 16 * r) * LSTR + k4 * 4];
#pragma unroll
            for (int c = 0; c < 8; ++c)
                wr[c] = *(const float4*)&ws[(tj + 16 * c) * LSTR + k4 * 4];
            wt = *(const float4*)&ws[(128 + tjt) * LSTR + k4 * 4];
#pragma unroll
            for (int r = 0; r < 4; ++r) {
#pragma unroll
                for (int c = 0; c < 8; ++c) {
                    acc[r][c] = fmaf(xr[r].x, wr[c].x, acc[r][c]);
                    acc[r][c] = fmaf(xr[r].y, wr[c].y, acc[r][c]);
                    acc[r][c] = fmaf(xr[r].z, wr[c].z, acc[r][c]);
                    acc[r][c] = fmaf(xr[r].w, wr[c].w, acc[r][c]);
                }
                acct[r] = fmaf(xr[r].x, wt.x, acct[r]);
                acct[r] = fmaf(xr[r].y, wt.y, acct[r]);
                acct[r] = fmaf(xr[r].z, wt.z, acct[r]);
                acct[r] = fmaf(xr[r].w, wt.w, acct[r]);
            }
        }
    }

#pragma unroll
    for (int c = 0; c < 8; ++c) {
        int j = tj + 16 * c;
        float bv = bias[j];
#pragma unroll
        for (int r = 0; r < 4; ++r)
            feats[(size_t)(m0 + tm + 16 * r) * CP + j] = acc[r][c] + bv;
    }
    if (tail) {
        int j = 128 + tj;
        float bv = bias[j];
#pragma unroll
        for (int r = 0; r < 4; ++r)
            feats[(size_t)(m0 + tm + 16 * r) * CP + j] = acct[r] + bv;
    }
}

// ---------------- Kernel 2: Viterbi forward v8 -----------------------------------------
// 64 blocks x 256 threads (4 waves). wave -> (h = wave>>1: i-half, jg = wave&1: j-group).
// Lane scans column j = jg*64+lane over i in [h*64, h*64+64) (+ i=128..131 for h=1) with a
// REGISTER-RESIDENT 68-float T half-row and readlane fan-out from sa (the lane's own
// carried state s[c], c = h*64+lane). Waves exchange partial maxes via double-buffered
// pbuf (stride-1, conflict-free). ONE lgkm barrier per step. Tail cols 128..130: six
// (tj,h) units as 64-wide candidate rows + shfl_xor max tree; h=1 waves rebuild the
// uniform sv = s[128..131] in-register. All max trees exact => hist bit-identical.
__global__ __launch_bounds__(256, 1) void viterbi_fwd(
    const float* __restrict__ feats, const float* __restrict__ mask,
    const float* __restrict__ trans, float* __restrict__ hist)
{
    const int b = blockIdx.x;
    const int tid = threadIdx.x;
    const int wave = tid >> 6, lane = tid & 63;
    const int h  = wave >> 1;           // i-half this wave scans / carries
    const int jg = wave & 1;            // j-group this wave scans
    const int j  = jg * 64 + lane;      // scan column (partial producer)
    const int c  = h * 64 + lane;       // state column carried in sa

    __shared__ float pbuf[2][2][132];   // [cur][h][j]
    __shared__ float tpbuf[2][3][2];    // [cur][tj-128][h]

    // ---- T half-row: 17 float4 = 68 floats (resident per rounds 4/5 evidence)
    float4 T[17];
    {
        const float* tr = trans + (size_t)j * CC + h * 64;
#pragma unroll
        for (int q = 0; q < 16; ++q) {
            T[q].x = tr[4 * q + 0]; T[q].y = tr[4 * q + 1];
            T[q].z = tr[4 * q + 2]; T[q].w = tr[4 * q + 3];
        }
        if (h == 0) {
            T[16] = make_float4(NEGV, NEGV, NEGV, NEGV);     // unused half-slot
        } else {
            T[16].x = tr[64]; T[16].y = tr[65]; T[16].z = tr[66];  // i = 128..130
            T[16].w = NEGV;                                   // i = 131 pad
        }
    }
#pragma unroll
    for (int q = 0; q < 17; ++q)
        asm volatile("" : "+v"(T[q].x), "+v"(T[q].y), "+v"(T[q].z), "+v"(T[q].w));

    // ---- tail unit T values (1 float per unit per lane)
    // jg==0 waves: units tj=128,129 ; jg==1 waves: unit tj=130 (each over own h-range)
    const int tjA = (jg == 0) ? 128 : 130;
    const bool hasB = (jg == 0);
    float ttA = trans[(size_t)tjA * CC + h * 64 + lane];            // i = h*64+lane <= 127
    float ttB = hasB ? trans[(size_t)129 * CC + h * 64 + lane] : NEGV;
    float ttxA = NEGV, ttxB = NEGV;                                  // i = 128+lane extras
    if (h == 1 && lane < 3) {
        ttxA = trans[(size_t)tjA * CC + 128 + lane];
        if (hasB) ttxB = trans[(size_t)129 * CC + 128 + lane];
    }

    const float* fb = feats + (size_t)b * LL * CP;
    const float* mb = mask + (size_t)b * LL;
    float* hb = hist + (size_t)b * LL * CP;

    // ---- register-carried state
    float  sa = NEGV;                                  // s[c], c<=127 never START
    float4 sv = make_float4(NEGV, 0.f, NEGV, NEGV);    // s[128],s[129]=START=0,s[130],pad
    float  st = (lane == 1) ? 0.f : NEGV;              // s[128+lane] on h=1 lanes 0..2

    const bool tl = (h == 1 && lane < 3);              // tail blend lanes

    // depth-2 prefetch rings
    float fv0 = fb[c], fv1 = fb[CP + c];
    float mv0 = mb[0], mv1 = mb[1];
    float ft0 = 0.f, ft1 = 0.f;
    if (tl) { ft0 = fb[128 + lane]; ft1 = fb[CP + 128 + lane]; }
    const float* fb_t  = fb + 2 * CP + c;
    const float* ftb_t = fb + 2 * CP + 128 + lane;
    const float* mb_t  = mb + 2;

    int cur = 0;
    for (int t = 0; t < LL; ++t) {
        // prefetch t+2
        float fv2 = 0.f, mv2 = 1.f, ft2 = 0.f;
        if (t + 2 < LL) { fv2 = *fb_t; mv2 = *mb_t; if (tl) ft2 = *ftb_t; }
        fb_t += CP; ftb_t += CP; ++mb_t;

        // ---- scan: partial max for column j over my i-half (zero LDS reads)
        float a0 = -3.0e38f, a1 = -3.0e38f, a2 = -3.0e38f, a3 = -3.0e38f;
#pragma unroll
        for (int q = 0; q < 8; ++q) {
            float4 t4 = T[q];
            a0 = fmaxf(fmaxf(RL(sa, 4 * q + 0) + t4.x, RL(sa, 4 * q + 1) + t4.y), a0);
            a1 = fmaxf(fmaxf(RL(sa, 4 * q + 2) + t4.z, RL(sa, 4 * q + 3) + t4.w), a1);
        }
#pragma unroll
        for (int q = 8; q < 16; ++q) {
            float4 t4 = T[q];
            a2 = fmaxf(fmaxf(RL(sa, 4 * q + 0) + t4.x, RL(sa, 4 * q + 1) + t4.y), a2);
            a3 = fmaxf(fmaxf(RL(sa, 4 * q + 2) + t4.z, RL(sa, 4 * q + 3) + t4.w), a3);
        }
        if (h == 1) {
            float4 t4 = T[16];
            a0 = fmaxf(fmaxf(sv.x + t4.x, sv.y + t4.y), a0);
            a1 = fmaxf(fmaxf(sv.z + t4.z, sv.w + t4.w), a1);   // pad: NEGV+NEGV, harmless
        }
        float p = fmaxf(fmaxf(a0, a1), fmaxf(a2, a3));
        pbuf[cur][h][j] = p;

        // ---- tail units: 64-wide candidate rows + butterfly max
        {
            float cA = sa + ttA;
            if (h == 1 && lane < 3) {
                float svl = (lane == 0) ? sv.x : ((lane == 1) ? sv.y : sv.z);
                cA = fmaxf(cA, svl + ttxA);
            }
#pragma unroll
            for (int off = 1; off < 64; off <<= 1)
                cA = fmaxf(cA, __shfl_xor(cA, off, 64));
            if (lane == 0) tpbuf[cur][tjA - 128][h] = cA;
            if (hasB) {
                float cB = sa + ttB;
                if (h == 1 && lane < 3) {
                    float svl = (lane == 0) ? sv.x : ((lane == 1) ? sv.y : sv.z);
                    cB = fmaxf(cB, svl + ttxB);
                }
#pragma unroll
                for (int off = 1; off < 64; off <<= 1)
                    cB = fmaxf(cB, __shfl_xor(cB, off, 64));
                if (lane == 0) tpbuf[cur][1][h] = cB;
            }
        }

        lds_barrier();   // partials published; double-buffer prevents WAR next step

        // ---- update: new s for column c (redundant across the h-pair, identical bits)
        {
            float best = fmaxf(pbuf[cur][0][c], pbuf[cur][1][c]);
            float ns = (mv0 != 0.f) ? (best + fv0) : sa;
            sa = ns;
            if (wave == 0 || wave == 2) hb[(size_t)t * CP + c] = ns;
        }
        // ---- tail update (h=1 waves rebuild sv; w3 stores tail hist)
        if (h == 1) {
            float2 u0 = *(const float2*)&tpbuf[cur][0][0];
            float2 u1 = *(const float2*)&tpbuf[cur][1][0];
            float2 u2 = *(const float2*)&tpbuf[cur][2][0];
            float c128 = fmaxf(u0.x, u0.y);
            float c129 = fmaxf(u1.x, u1.y);
            float c130 = fmaxf(u2.x, u2.y);
            if (lane < 3) {
                float comb = (lane == 0) ? c128 : ((lane == 1) ? c129 : c130);
                float nst = (mv0 != 0.f) ? (comb + ft0) : st;
                st = nst;
                if (wave == 3) hb[(size_t)t * CP + 128 + lane] = nst;
            }
            sv.x = RL(st, 0); sv.y = RL(st, 1); sv.z = RL(st, 2); sv.w = NEGV;
        }

        fv0 = fv1; fv1 = fv2; mv0 = mv1; mv1 = mv2; ft0 = ft1; ft1 = ft2;
        cur ^= 1;
    }
}

// ---------------- Kernel 3: backpointer matrix (unchanged) ----------------
__global__ __launch_bounds__(256, 4) void bp_kernel(
    const float* __restrict__ hist, const float* __restrict__ trans,
    unsigned char* __restrict__ bp)
{
    const int b  = blockIdx.x / 5;
    const int jc = blockIdx.x % 5;
    const int tc = blockIdx.y;
    const int tid = threadIdx.x;
    const int j0 = jc * 32;

    __shared__ float Ts[32][136];
    __shared__ float hs[8][132];

    for (int q = 0; q < 17; ++q) {
        int lin = tid + q * 256;
        if (lin < 32 * CC) {
            int r = lin / CC, i = lin - r * CC;
            if (j0 + r < CC) Ts[r][i] = trans[(size_t)(j0 + r) * CC + i];
        }
    }
    {
        const float4* src = (const float4*)(hist + ((size_t)b * LL + tc * 8) * CP);
#pragma unroll
        for (int q = 0; q < 2; ++q) {
            int lin = tid + q * 256;
            if (lin < (8 * CP) / 4) ((float4*)hs)[lin] = src[lin];
        }
    }
    __syncthreads();

    const int jl = tid & 31;
    const int tt = tid >> 5;
    const int j = j0 + jl;
    const int t = tc * 8 + tt + 1;
    if (j >= CC || t >= LL) return;

    float best; int idx;
    {
        float4 tv = *(const float4*)&Ts[jl][128];
        float4 hv = *(const float4*)&hs[tt][128];
        best = hv.z + tv.z; idx = 130;
        float v;
        v = hv.y + tv.y; if (v >= best) { best = v; idx = 129; }
        v = hv.x + tv.x; if (v >= best) { best = v; idx = 128; }
    }
#pragma unroll
    for (int i4 = 31; i4 >= 0; --i4) {
        float4 tv = *(const float4*)&Ts[jl][i4 * 4];
        float4 hv = *(const float4*)&hs[tt][i4 * 4];
        float v;
        v = hv.w + tv.w; if (v >= best) { best = v; idx = i4 * 4 + 3; }
        v = hv.z + tv.z; if (v >= best) { best = v; idx = i4 * 4 + 2; }
        v = hv.y + tv.y; if (v >= best) { best = v; idx = i4 * 4 + 1; }
        v = hv.x + tv.x; if (v >= best) { best = v; idx = i4 * 4 + 0; }
    }
    bp[((size_t)b * LL + t) * CP + j] = (unsigned char)idx;
}

// ---------------- Kernel 4: final argmax + LDS-streamed u8 backtrack (unchanged) ------
__global__ __launch_bounds__(64, 1) void viterbi_btr(
    const float* __restrict__ hist, const float* __restrict__ trans,
    const unsigned char* __restrict__ bp,
    float* __restrict__ out_score, float* __restrict__ out_path)
{
    const int b = blockIdx.x;
    const int lane = threadIdx.x;
    const float* hb = hist + ((size_t)b * LL + (LL - 1)) * CP;
    const float* ts = trans + (size_t)STOP_I * CC;

    float v0 = hb[lane] + ts[lane];
    float v1 = hb[lane + 64] + ts[lane + 64];
    float v2 = (lane < 3) ? (hb[lane + 128] + ts[lane + 128]) : -3.0e38f;

    float best = v0; int idx = lane;
    if (v1 > best) { best = v1; idx = lane + 64; }
    if (v2 > best) { best = v2; idx = lane + 128; }
#pragma unroll
    for (int off = 32; off >= 1; off >>= 1) {
        float ob = __shfl_xor(best, off, 64);
        int   oi = __shfl_xor(idx, off, 64);
        if (ob > best || (ob == best && oi < idx)) { best = ob; idx = oi; }
    }

    float* op = out_path + (size_t)b * LL;
    if (lane == 0) {
        out_score[b] = best;
        op[LL - 1] = (float)idx;
    }
    int tag = idx;

    __shared__ unsigned char buf[2][1088];
    const unsigned char* bpb = bp + (size_t)b * LL * CP;

    {
        const unsigned int* src = (const unsigned int*)(bpb + (size_t)504 * CP);
        unsigned int* dst = (unsigned int*)buf[1];
#pragma unroll
        for (int q = 0; q < 5; ++q) {
            int lin = lane + q * 64;
            if (lin < 264) dst[lin] = src[lin];
        }
    }
    lds_barrier();

    int cur = 1;
    for (int k = 63; k >= 0; --k) {
        unsigned int r0 = 0, r1 = 0, r2 = 0, r3 = 0, r4 = 0;
        if (k > 0) {
            const unsigned int* src = (const unsigned int*)(bpb + (size_t)(k - 1) * 8 * CP);
            r0 = src[lane];
            r1 = src[lane + 64];
            r2 = src[lane + 128];
            r3 = src[lane + 192];
            if (lane < 8) r4 = src[lane + 256];
        }
        const unsigned char* cb = buf[cur];
#pragma unroll
        for (int s = 7; s >= 0; --s) {
            int t = k * 8 + s;
            if (t >= 1) {
                tag = cb[s * CP + tag];
                if (lane == 0) op[t - 1] = (float)tag;
            }
        }
        if (k > 0) {
            unsigned int* dst = (unsigned int*)buf[cur ^ 1];
            dst[lane] = r0;
            dst[lane + 64] = r1;
            dst[lane + 128] = r2;
            dst[lane + 192] = r3;
            if (lane < 8) dst[lane + 256] = r4;
            lds_barrier();
        }
        cur ^= 1;
    }
}

extern "C" void kernel_launch(void* const* d_in, const int* in_sizes, int n_in,
                              void* d_out, int out_size, void* d_ws, size_t ws_size,
                              hipStream_t stream)
{
    const float* x     = (const float*)d_in[0];
    const float* mask  = (const float*)d_in[1];
    const float* W     = (const float*)d_in[2];
    const float* bias  = (const float*)d_in[3];
    const float* trans = (const float*)d_in[4];

    float* feats = (float*)d_ws;
    float* hist  = feats + (size_t)BB * LL * CP;
    unsigned char* bp = (unsigned char*)(hist + (size_t)BB * LL * CP);
    float* out_score = (float*)d_out;
    float* out_path  = out_score + BB;

    hipLaunchKernelGGL(gemm_feats, dim3((BB * LL) / GM), dim3(256), 0, stream, x, W, bias, feats);
    hipLaunchKernelGGL(viterbi_fwd, dim3(BB), dim3(256), 0, stream, feats, mask, trans, hist);
    hipLaunchKernelGGL(bp_kernel, dim3(BB * 5, 64), dim3(256), 0, stream, hist, trans, bp);
    hipLaunchKernelGGL(viterbi_btr, dim3(BB), dim3(64), 0, stream, hist, trans, bp, out_score, out_path);
}